// Round 10
// baseline (495.373 us; speedup 1.0000x reference)
//
#include <hip/hip_runtime.h>
#include <stdint.h>

// Problem constants
#define kB  16384
#define kD  1024
#define kDE 512

typedef __bf16 bf16x8 __attribute__((ext_vector_type(8)));
typedef float  f32x4  __attribute__((ext_vector_type(4)));

__device__ __forceinline__ unsigned short f2bf(float f) {
    union { float f; unsigned u; } v; v.f = f;
    unsigned r = v.u + 0x7FFFu + ((v.u >> 16) & 1u);   // round-to-nearest-even
    return (unsigned short)(r >> 16);
}

__device__ __forceinline__ void async16(unsigned short* lds, const unsigned short* g) {
    __builtin_amdgcn_global_load_lds(
        (const __attribute__((address_space(1))) unsigned int*)g,
        (__attribute__((address_space(3))) unsigned int*)lds, 16, 0, 0);
}

// ---------------- prep: transpose + convert weights to bf16 ----------------
__global__ __launch_bounds__(256) void prep_w(const float* __restrict__ Wsh,
                                              const float* __restrict__ Wsp,
                                              unsigned short* __restrict__ Wt) {
    __shared__ float tile[64][65];
    const int slot = blockIdx.z;
    const int k0 = blockIdx.x * 64;
    const int n0 = blockIdx.y * 64;
    const float* src = (slot < 4) ? (Wsh + (size_t)slot * kD * kDE)
                                  : (Wsp + (size_t)(slot - 4) * kD * kDE);
    const int tid = threadIdx.x;
    const int lr = tid >> 4, lc = (tid & 15) * 4;
#pragma unroll
    for (int i = 0; i < 4; i++) {
        const float4 v = *(const float4*)&src[(size_t)(k0 + lr + i * 16) * kDE + n0 + lc];
        tile[lr + i * 16][lc + 0] = v.x;
        tile[lr + i * 16][lc + 1] = v.y;
        tile[lr + i * 16][lc + 2] = v.z;
        tile[lr + i * 16][lc + 3] = v.w;
    }
    __syncthreads();
    const int wn = tid >> 2, wk = (tid & 3) * 16;
    unsigned short* dst = Wt + (size_t)slot * kDE * kD + (size_t)(n0 + wn) * kD + k0 + wk;
#pragma unroll
    for (int j = 0; j < 4; j++) {
        ushort4 h;
        h.x = f2bf(tile[wk + j * 4 + 0][wn]);
        h.y = f2bf(tile[wk + j * 4 + 1][wn]);
        h.z = f2bf(tile[wk + j * 4 + 2][wn]);
        h.w = f2bf(tile[wk + j * 4 + 3][wn]);
        *(ushort4*)(dst + j * 4) = h;
    }
}

// ------------- fused x fp32->bf16 conversion + gate softmax ---------------
__global__ __launch_bounds__(256) void conv_gate(
    const float* __restrict__ x0, const float* __restrict__ x1,
    const float* __restrict__ Wg, const float* __restrict__ bg,
    unsigned short* __restrict__ xb, float* __restrict__ g) {
    const int wid = threadIdx.x >> 6, lane = threadIdx.x & 63;
    const int r = blockIdx.x * 4 + wid;
    const int t = r >> 14, b = r & 16383;
    const float* xrow = (t ? x1 : x0) + (size_t)b * kD;
    unsigned short* xbrow = xb + (size_t)(t * kB + b) * kD;
    const float* Wgt = Wg + t * kD * 8;
    float p[8] = {0.f,0.f,0.f,0.f,0.f,0.f,0.f,0.f};
#pragma unroll
    for (int it = 0; it < 4; it++) {
        const int d0 = it * 256 + lane * 4;
        const float4 v = *(const float4*)(xrow + d0);
        ushort4 h;
        h.x = f2bf(v.x); h.y = f2bf(v.y); h.z = f2bf(v.z); h.w = f2bf(v.w);
        *(ushort4*)(xbrow + d0) = h;
        const float xv[4] = {v.x, v.y, v.z, v.w};
#pragma unroll
        for (int j = 0; j < 4; j++) {
            const float* wrow = Wgt + (size_t)(d0 + j) * 8;
            const float4 wa = *(const float4*)wrow;
            const float4 wb = *(const float4*)(wrow + 4);
            p[0] += xv[j] * wa.x; p[1] += xv[j] * wa.y;
            p[2] += xv[j] * wa.z; p[3] += xv[j] * wa.w;
            p[4] += xv[j] * wb.x; p[5] += xv[j] * wb.y;
            p[6] += xv[j] * wb.z; p[7] += xv[j] * wb.w;
        }
    }
#pragma unroll
    for (int e = 0; e < 8; e++) {
        float v = p[e];
#pragma unroll
        for (int s = 1; s < 64; s <<= 1) v += __shfl_xor(v, s, 64);
        p[e] = v;
    }
    float lg[8];
#pragma unroll
    for (int e = 0; e < 8; e++) lg[e] = p[e] + bg[t * 8 + e];
    float mx = lg[0];
#pragma unroll
    for (int e = 1; e < 8; e++) mx = fmaxf(mx, lg[e]);
    float s = 0.f;
#pragma unroll
    for (int e = 0; e < 8; e++) { lg[e] = __expf(lg[e] - mx); s += lg[e]; }
    const float inv = 1.f / s;
    if (lane == 0) {
        float* gp = g + (size_t)(t * kB + b) * 8;
        float4 g0 = {lg[0]*inv, lg[1]*inv, lg[2]*inv, lg[3]*inv};
        float4 g1 = {lg[4]*inv, lg[5]*inv, lg[6]*inv, lg[7]*inv};
        *(float4*)gp = g0;
        *(float4*)(gp + 4) = g1;
    }
}

// ---------------- fused MoE GEMM (2 blocks/CU, 64-row tiles) ---------------
// Block: 64 rows x (8 experts x 64 cols), BK=32, 8 waves (2M x 4N),
// per-wave 32 rows x 16 cols x 8 experts -> acc[8][2] = 64 VGPR.
// LDS 72 KB double-buffered -> 2 blocks/CU: the co-resident block's MFMA
// fills this block's stall windows (m114 overlap mechanism).
// RACE FIX vs R9: raw s_barrier is NOT a compiler memory fence; ds_reads and
// global_load_lds writes were moving across it (intermittent replay
// divergence). sched_barrier(0) pins every memory op inside its phase window:
//   barrier -> sched_barrier -> COMPUTE -> sched_barrier -> barrier.
__global__ __launch_bounds__(512, 4) void moe_gemm(
    const unsigned short* __restrict__ xb, const unsigned short* __restrict__ Wt,
    const float* __restrict__ g, const float* __restrict__ bsh,
    const float* __restrict__ bsp, float* __restrict__ out) {
    __shared__ __align__(16) unsigned short As[2][64 * 32];       // 2 x 4 KB
    __shared__ __align__(16) unsigned short Bs[2][8 * 64 * 32];   // 2 x 32 KB

    // XCD-bijective swizzle (nwg=4096, %8==0)
    const int bid = blockIdx.x;
    const int w = (bid & 7) * 512 + (bid >> 3);
    const int ct = w & 7;
    const int rw = (w >> 3) & 255;
    const int t  = w >> 11;
    const int rowBase = rw * 64, n0 = ct * 64;

    const int tid = threadIdx.x, wid = tid >> 6, lane = tid & 63;
    const int wr = wid >> 2, wc = wid & 3;
    const bool hasA = (wid < 4);

    // staging source (pair-line pre-swizzle — address math verified in R8)
    const int dSt = (lane & 7) ^ (lane >> 3);
    const unsigned short* aS = xb + (size_t)t * kB * kD +
        (size_t)(rowBase + wid * 16 + (lane >> 3) * 2 + (dSt >> 2)) * kD + (dSt & 3) * 8;
    const int slot = (wid < 4) ? wid : (4 + t * 4 + (wid - 4));
    const unsigned short* bS = Wt + (size_t)slot * kDE * kD +
        (size_t)(n0 + (lane >> 3) * 2 + (dSt >> 2)) * kD + (dSt & 3) * 8;

    // fragment read offsets (pair-line swizzled — verified in R8)
    const int l15h = (lane & 15) >> 1;
    const int swR = (((lane & 1) * 4 + (lane >> 4)) ^ l15h);
    const int aRd = wr * 1024 + l15h * 64 + swR * 8;    // + m*512
    const int bRd = wc * 512  + l15h * 64 + swR * 8;    // + e*2048
    const int kg  = lane >> 4;

    f32x4 acc[8][2];
#pragma unroll
    for (int e = 0; e < 8; e++)
#pragma unroll
        for (int m = 0; m < 2; m++) acc[e][m] = (f32x4){0.f, 0.f, 0.f, 0.f};

#define STAGE(buf, ktn)                                                        \
    {                                                                          \
        if (hasA) async16(&As[buf][wid * 512], aS + (ktn) * 32);               \
        _Pragma("unroll")                                                      \
        for (int j = 0; j < 4; j++)                                            \
            async16(&Bs[buf][wid * 2048 + j * 512],                            \
                    bS + (size_t)j * 16 * kD + (ktn) * 32);                    \
    }

#define WAITP                                                                  \
    if (hasA) { asm volatile("s_waitcnt vmcnt(5)" ::: "memory"); }             \
    else      { asm volatile("s_waitcnt vmcnt(4)" ::: "memory"); }

#define COMPUTE(buf)                                                           \
    {                                                                          \
        bf16x8 af[2], bfr[4];                                                  \
        _Pragma("unroll")                                                      \
        for (int m = 0; m < 2; m++)                                            \
            af[m] = *(const bf16x8*)&As[buf][aRd + m * 512];                   \
        _Pragma("unroll")                                                      \
        for (int c = 0; c < 2; c++) {                                          \
            _Pragma("unroll")                                                  \
            for (int i = 0; i < 4; i++)                                        \
                bfr[i] = *(const bf16x8*)&Bs[buf][bRd + (c * 4 + i) * 2048];   \
            _Pragma("unroll")                                                  \
            for (int i = 0; i < 4; i++)                                        \
                _Pragma("unroll")                                              \
                for (int m = 0; m < 2; m++)                                    \
                    acc[c * 4 + i][m] = __builtin_amdgcn_mfma_f32_16x16x32_bf16( \
                        af[m], bfr[i], acc[c * 4 + i][m], 0, 0, 0);            \
        }                                                                      \
    }

// Pinned compute window: no LDS read escapes upward past the entry barrier,
// no read/stage crosses the exit barrier.
#define COMPUTE_PINNED(buf)                                                    \
    __builtin_amdgcn_s_barrier();                                              \
    __builtin_amdgcn_sched_barrier(0);                                         \
    COMPUTE(buf);                                                              \
    __builtin_amdgcn_sched_barrier(0);                                         \
    __builtin_amdgcn_s_barrier();

    // prologue: stage tile 0 into buf 0 (drained by first WAITP in the loop)
    STAGE(0, 0);
    for (int kt2 = 0; kt2 < 16; ++kt2) {
        STAGE(1, kt2 * 2 + 1);
        WAITP;
        COMPUTE_PINNED(0);
        STAGE(0, (kt2 * 2 + 2) & 31);          // last iter restages t0 (benign)
        WAITP;
        COMPUTE_PINNED(1);
    }
    asm volatile("s_waitcnt vmcnt(0)" ::: "memory");

#undef STAGE
#undef WAITP
#undef COMPUTE
#undef COMPUTE_PINNED

    // ---- epilogue: out = sum_e g_e * relu(acc[e] + bias_e) ----
    const int col = n0 + wc * 16 + (lane & 15);
    float bv[8];
#pragma unroll
    for (int e = 0; e < 8; e++)
        bv[e] = (e < 4) ? bsh[e * kDE + col] : bsp[(t * 4 + (e - 4)) * kDE + col];

#pragma unroll
    for (int m = 0; m < 2; m++) {
        const int r0 = rowBase + wr * 32 + m * 16 + kg * 4;
#pragma unroll
        for (int q = 0; q < 4; q++) {
            const float* gp = g + ((size_t)t * kB + r0 + q) * 8;
            const float4 ga = *(const float4*)gp;
            const float4 gb = *(const float4*)(gp + 4);
            float s = ga.x * fmaxf(acc[0][m][q] + bv[0], 0.f)
                    + ga.y * fmaxf(acc[1][m][q] + bv[1], 0.f)
                    + ga.z * fmaxf(acc[2][m][q] + bv[2], 0.f)
                    + ga.w * fmaxf(acc[3][m][q] + bv[3], 0.f)
                    + gb.x * fmaxf(acc[4][m][q] + bv[4], 0.f)
                    + gb.y * fmaxf(acc[5][m][q] + bv[5], 0.f)
                    + gb.z * fmaxf(acc[6][m][q] + bv[6], 0.f)
                    + gb.w * fmaxf(acc[7][m][q] + bv[7], 0.f);
            out[((size_t)(r0 + q) * 2 + t) * kDE + col] = s;
        }
    }
}

extern "C" void kernel_launch(void* const* d_in, const int* in_sizes, int n_in,
                              void* d_out, int out_size, void* d_ws, size_t ws_size,
                              hipStream_t stream) {
    const float* x0  = (const float*)d_in[0];
    const float* x1  = (const float*)d_in[1];
    const float* Wsh = (const float*)d_in[2];
    const float* bsh = (const float*)d_in[3];
    const float* Wsp = (const float*)d_in[4];
    const float* bsp = (const float*)d_in[5];
    const float* Wg  = (const float*)d_in[6];
    const float* bg  = (const float*)d_in[7];
    float* out = (float*)d_out;

    // ws layout (bytes): xb 67108864 | Wt 12582912 | g 1048576
    char* ws = (char*)d_ws;
    unsigned short* xb = (unsigned short*)ws;
    unsigned short* Wt = (unsigned short*)(ws + 67108864);
    float* g  = (float*)(ws + 67108864 + 12582912);

    prep_w<<<dim3(16, 8, 12), dim3(256), 0, stream>>>(Wsh, Wsp, Wt);
    conv_gate<<<dim3(8192), dim3(256), 0, stream>>>(x0, x1, Wg, bg, xb, g);
    moe_gemm<<<dim3(4096), dim3(512), 0, stream>>>(xb, Wt, g, bsh, bsp, out);
}

// Round 11
// 429.288 us; speedup vs baseline: 1.1539x; 1.1539x over previous
//
#include <hip/hip_runtime.h>
#include <stdint.h>

// Problem constants
#define kB  16384
#define kD  1024
#define kDE 512

typedef __bf16 bf16x8 __attribute__((ext_vector_type(8)));
typedef float  f32x4  __attribute__((ext_vector_type(4)));

__device__ __forceinline__ unsigned short f2bf(float f) {
    union { float f; unsigned u; } v; v.f = f;
    unsigned r = v.u + 0x7FFFu + ((v.u >> 16) & 1u);   // round-to-nearest-even
    return (unsigned short)(r >> 16);
}

__device__ __forceinline__ void async16(unsigned short* lds, const unsigned short* g) {
    __builtin_amdgcn_global_load_lds(
        (const __attribute__((address_space(1))) unsigned int*)g,
        (__attribute__((address_space(3))) unsigned int*)lds, 16, 0, 0);
}

// ---------- prep: weights -> fragment-major bf16 Wf ----------
// Wf[slot][kc=0..31][nt=0..31][lane=0..63][j=0..7] (each frag 1 KB contiguous)
// element = W[slot][ kc*32 + (lane>>4)*8 + j ][ nt*16 + (lane&15) ]
// GEMM B-frag load becomes: base + lane*16B  -> perfectly coalesced.
__global__ __launch_bounds__(256) void prep_wf(const float* __restrict__ Wsh,
                                               const float* __restrict__ Wsp,
                                               unsigned short* __restrict__ Wf) {
    __shared__ float tile[32][512];              // 64 KB
    const int kc = blockIdx.x;                   // 0..31
    const int slot = blockIdx.y;                 // 0..11
    const float* src = ((slot < 4) ? (Wsh + (size_t)slot * kD * kDE)
                                   : (Wsp + (size_t)(slot - 4) * kD * kDE))
                       + (size_t)kc * 32 * kDE;
    const int tid = threadIdx.x;
#pragma unroll
    for (int i = 0; i < 16; i++) {
        const int idx = i * 256 + tid;           // 0..4095
        const int row = idx >> 7;                // k-local 0..31
        const int c4 = (idx & 127) << 2;
        const float4 v = *(const float4*)&src[(size_t)row * kDE + c4];
        tile[row][c4 + 0] = v.x; tile[row][c4 + 1] = v.y;
        tile[row][c4 + 2] = v.z; tile[row][c4 + 3] = v.w;
    }
    __syncthreads();
    const int nt = tid >> 3;                     // 0..31
    const int l0 = (tid & 7) * 8;                // 8 lanes per thread
    unsigned short* dst = Wf + ((size_t)(slot * 32 + kc) * 32 + nt) * 512;
#pragma unroll
    for (int li = 0; li < 8; li++) {
        const int l = l0 + li;
        const int col = nt * 16 + (l & 15);
        const int kb = (l >> 4) * 8;
        ushort4 ha, hb;
        ha.x = f2bf(tile[kb + 0][col]); ha.y = f2bf(tile[kb + 1][col]);
        ha.z = f2bf(tile[kb + 2][col]); ha.w = f2bf(tile[kb + 3][col]);
        hb.x = f2bf(tile[kb + 4][col]); hb.y = f2bf(tile[kb + 5][col]);
        hb.z = f2bf(tile[kb + 6][col]); hb.w = f2bf(tile[kb + 7][col]);
        *(ushort4*)(dst + l * 8) = ha;
        *(ushort4*)(dst + l * 8 + 4) = hb;
    }
}

// ------------- fused x fp32->bf16 conversion + gate softmax ---------------
__global__ __launch_bounds__(256) void conv_gate(
    const float* __restrict__ x0, const float* __restrict__ x1,
    const float* __restrict__ Wg, const float* __restrict__ bg,
    unsigned short* __restrict__ xb, float* __restrict__ g) {
    const int wid = threadIdx.x >> 6, lane = threadIdx.x & 63;
    const int r = blockIdx.x * 4 + wid;
    const int t = r >> 14, b = r & 16383;
    const float* xrow = (t ? x1 : x0) + (size_t)b * kD;
    unsigned short* xbrow = xb + (size_t)(t * kB + b) * kD;
    const float* Wgt = Wg + t * kD * 8;
    float p[8] = {0.f,0.f,0.f,0.f,0.f,0.f,0.f,0.f};
#pragma unroll
    for (int it = 0; it < 4; it++) {
        const int d0 = it * 256 + lane * 4;
        const float4 v = *(const float4*)(xrow + d0);
        ushort4 h;
        h.x = f2bf(v.x); h.y = f2bf(v.y); h.z = f2bf(v.z); h.w = f2bf(v.w);
        *(ushort4*)(xbrow + d0) = h;
        const float xv[4] = {v.x, v.y, v.z, v.w};
#pragma unroll
        for (int j = 0; j < 4; j++) {
            const float* wrow = Wgt + (size_t)(d0 + j) * 8;
            const float4 wa = *(const float4*)wrow;
            const float4 wb = *(const float4*)(wrow + 4);
            p[0] += xv[j] * wa.x; p[1] += xv[j] * wa.y;
            p[2] += xv[j] * wa.z; p[3] += xv[j] * wa.w;
            p[4] += xv[j] * wb.x; p[5] += xv[j] * wb.y;
            p[6] += xv[j] * wb.z; p[7] += xv[j] * wb.w;
        }
    }
#pragma unroll
    for (int e = 0; e < 8; e++) {
        float v = p[e];
#pragma unroll
        for (int s = 1; s < 64; s <<= 1) v += __shfl_xor(v, s, 64);
        p[e] = v;
    }
    float lg[8];
#pragma unroll
    for (int e = 0; e < 8; e++) lg[e] = p[e] + bg[t * 8 + e];
    float mx = lg[0];
#pragma unroll
    for (int e = 1; e < 8; e++) mx = fmaxf(mx, lg[e]);
    float s = 0.f;
#pragma unroll
    for (int e = 0; e < 8; e++) { lg[e] = __expf(lg[e] - mx); s += lg[e]; }
    const float inv = 1.f / s;
    if (lane == 0) {
        float* gp = g + (size_t)(t * kB + b) * 8;
        float4 g0 = {lg[0]*inv, lg[1]*inv, lg[2]*inv, lg[3]*inv};
        float4 g1 = {lg[4]*inv, lg[5]*inv, lg[6]*inv, lg[7]*inv};
        *(float4*)gp = g0;
        *(float4*)(gp + 4) = g1;
    }
}

// ------------- fused MoE GEMM: B direct global->reg, A via LDS -------------
// M=128 x (8 experts x 64 cols), 8 waves (2M x 4N), BK=64, 16 steps.
// B-fragments loaded from fragment-major Wf straight into registers,
// software-pipelined one step ahead (issued mid-step k-1, used step k).
// LDS holds only A (32 KB dbuf) -> per-step LDS traffic 80 KB (~940 cyc),
// vs 272 KB before: removes the LDS-serialization term identified in R10.
// Sync: one vmcnt(18)+barrier pair per step for the A dbuf (audited: the 2
// drained loads are exactly A(k), oldest in the queue); B/af deps are
// compiler-visible register dataflow (auto waitcnt).
__global__ __launch_bounds__(512, 2) void moe_gemm(
    const unsigned short* __restrict__ xb, const unsigned short* __restrict__ Wf,
    const float* __restrict__ g, const float* __restrict__ bsh,
    const float* __restrict__ bsp, float* __restrict__ out) {
    __shared__ __align__(16) unsigned short As[2][128 * 64];   // 32 KB

    // XCD-bijective swizzle (nwg=2048, %8==0)
    const int bid = blockIdx.x;
    const int swz = (bid & 7) * 256 + (bid >> 3);
    const int ct = swz & 7;
    const int rt = (swz >> 3) & 127;
    const int t  = swz >> 10;
    const int n0 = ct * 64;

    const int tid = threadIdx.x, wid = tid >> 6, lane = tid & 63;
    const int wr = wid >> 2, wc = wid & 3;

    // ---- A staging (R6-verified pre-swizzled source, linear LDS dest) ----
    const int swzChunk = ((lane & 7) ^ ((lane >> 3) & 7)) * 8;
    const unsigned short* aSrc = xb + (size_t)t * kB * kD +
        (size_t)(rt * 128 + wid * 16 + (lane >> 3)) * kD + swzChunk;
    // ---- A fragment reads (R6-verified) ----
    const int rAbase = (wr * 64 + (lane & 15)) * 64;
    const int lx = lane & 7;
    const int kg = lane >> 4;

    // ---- B direct-global fragment addressing ----
    const int nt = ct * 4 + wc;
    const bf16x8* wfL = (const bf16x8*)Wf + lane;   // + fragIdx*64
    int soff[8];
#pragma unroll
    for (int e = 0; e < 8; e++) {
        const int slotE = (e < 4) ? e : (4 + t * 4 + (e - 4));
        soff[e] = slotE * 65536 + nt * 64;          // (slot*32kc*32nt + nt) * 64
    }

    f32x4 acc[8][4];
#pragma unroll
    for (int e = 0; e < 8; e++)
#pragma unroll
        for (int m = 0; m < 4; m++) acc[e][m] = (f32x4){0.f, 0.f, 0.f, 0.f};

    bf16x8 b0[8], b1[8], af[4];

#define STAGE_A(buf, ktn)                                                      \
    async16(&As[buf][wid * 1024], aSrc + (ktn) * 64);                          \
    async16(&As[buf][wid * 1024 + 512], aSrc + (ktn) * 64 + 8 * kD);

#define LOADB(dst, kc)                                                         \
    _Pragma("unroll")                                                          \
    for (int e = 0; e < 8; e++) dst[e] = wfL[soff[e] + (kc) * 2048];

#define R_A(buf, ks)                                                           \
    _Pragma("unroll")                                                          \
    for (int m = 0; m < 4; m++)                                                \
        af[m] = *(const bf16x8*)&As[buf][rAbase + m * 1024 +                   \
                                         ((((ks) * 4 + kg) ^ lx) << 3)];

#define MFMA8(bset)                                                            \
    _Pragma("unroll")                                                          \
    for (int e = 0; e < 8; e++)                                                \
        _Pragma("unroll")                                                      \
        for (int m = 0; m < 4; m++)                                            \
            acc[e][m] = __builtin_amdgcn_mfma_f32_16x16x32_bf16(               \
                af[m], bset[e], acc[e][m], 0, 0, 0);

// One K-step: compute buf cur (A) + b0/b1 (B); stage A(ktn) into nxt;
// load B for tile ktn. vmcnt(18) drains exactly the A staged last step.
#define STEP(cur, nxt, ktn)                                                    \
    {                                                                          \
        STAGE_A(nxt, ktn);                                                     \
        asm volatile("s_waitcnt vmcnt(18)" ::: "memory");                      \
        __builtin_amdgcn_s_barrier();                                          \
        __builtin_amdgcn_sched_barrier(0);                                     \
        R_A(cur, 0);                                                           \
        MFMA8(b0);                                                             \
        LOADB(b0, (ktn) * 2);                                                  \
        R_A(cur, 1);                                                           \
        MFMA8(b1);                                                             \
        LOADB(b1, (ktn) * 2 + 1);                                              \
        __builtin_amdgcn_sched_barrier(0);                                     \
        __builtin_amdgcn_s_barrier();                                          \
    }

    // prologue: A tile0 -> buf0; B frags for tile 0
    STAGE_A(0, 0);
    LOADB(b0, 0);
    LOADB(b1, 1);

    for (int kt2 = 0; kt2 < 8; ++kt2) {
        STEP(0, 1, kt2 * 2 + 1)
        STEP(1, 0, (kt2 * 2 + 2) & 15)     // tail wraps to tile 0 (benign)
    }
    asm volatile("s_waitcnt vmcnt(0)" ::: "memory");

#undef STAGE_A
#undef LOADB
#undef R_A
#undef MFMA8
#undef STEP

    // ---- epilogue: out = sum_e g_e * relu(acc[e] + bias_e) ----
    const int col = n0 + wc * 16 + (lane & 15);
    float bv[8];
#pragma unroll
    for (int e = 0; e < 8; e++)
        bv[e] = (e < 4) ? bsh[e * kDE + col] : bsp[(t * 4 + (e - 4)) * kDE + col];

#pragma unroll
    for (int m = 0; m < 4; m++) {
        const int r0 = rt * 128 + wr * 64 + m * 16 + kg * 4;
#pragma unroll
        for (int q = 0; q < 4; q++) {
            const float* gp = g + ((size_t)t * kB + r0 + q) * 8;
            const float4 ga = *(const float4*)gp;
            const float4 gb = *(const float4*)(gp + 4);
            float s = ga.x * fmaxf(acc[0][m][q] + bv[0], 0.f)
                    + ga.y * fmaxf(acc[1][m][q] + bv[1], 0.f)
                    + ga.z * fmaxf(acc[2][m][q] + bv[2], 0.f)
                    + ga.w * fmaxf(acc[3][m][q] + bv[3], 0.f)
                    + gb.x * fmaxf(acc[4][m][q] + bv[4], 0.f)
                    + gb.y * fmaxf(acc[5][m][q] + bv[5], 0.f)
                    + gb.z * fmaxf(acc[6][m][q] + bv[6], 0.f)
                    + gb.w * fmaxf(acc[7][m][q] + bv[7], 0.f);
            out[((size_t)(r0 + q) * 2 + t) * kDE + col] = s;
        }
    }
}

extern "C" void kernel_launch(void* const* d_in, const int* in_sizes, int n_in,
                              void* d_out, int out_size, void* d_ws, size_t ws_size,
                              hipStream_t stream) {
    const float* x0  = (const float*)d_in[0];
    const float* x1  = (const float*)d_in[1];
    const float* Wsh = (const float*)d_in[2];
    const float* bsh = (const float*)d_in[3];
    const float* Wsp = (const float*)d_in[4];
    const float* bsp = (const float*)d_in[5];
    const float* Wg  = (const float*)d_in[6];
    const float* bg  = (const float*)d_in[7];
    float* out = (float*)d_out;

    // ws layout (bytes): xb 67108864 | Wf 12582912 | g 1048576
    char* ws = (char*)d_ws;
    unsigned short* xb = (unsigned short*)ws;
    unsigned short* Wf = (unsigned short*)(ws + 67108864);
    float* g  = (float*)(ws + 67108864 + 12582912);

    prep_wf<<<dim3(32, 12), dim3(256), 0, stream>>>(Wsh, Wsp, Wf);
    conv_gate<<<dim3(8192), dim3(256), 0, stream>>>(x0, x1, Wg, bg, xb, g);
    moe_gemm<<<dim3(2048), dim3(512), 0, stream>>>(xb, Wf, g, bsh, bsp, out);
}

// Round 12
// 413.626 us; speedup vs baseline: 1.1976x; 1.0379x over previous
//
#include <hip/hip_runtime.h>
#include <stdint.h>

// Problem constants
#define kB  16384
#define kD  1024
#define kDE 512

typedef __bf16 bf16x8 __attribute__((ext_vector_type(8)));
typedef float  f32x4  __attribute__((ext_vector_type(4)));

__device__ __forceinline__ unsigned short f2bf(float f) {
    union { float f; unsigned u; } v; v.f = f;
    unsigned r = v.u + 0x7FFFu + ((v.u >> 16) & 1u);   // round-to-nearest-even
    return (unsigned short)(r >> 16);
}

__device__ __forceinline__ void async16(unsigned short* lds, const unsigned short* g) {
    __builtin_amdgcn_global_load_lds(
        (const __attribute__((address_space(1))) unsigned int*)g,
        (__attribute__((address_space(3))) unsigned int*)lds, 16, 0, 0);
}

// ---------------- prep: transpose + convert weights to bf16 ----------------
__global__ __launch_bounds__(256) void prep_w(const float* __restrict__ Wsh,
                                              const float* __restrict__ Wsp,
                                              unsigned short* __restrict__ Wt) {
    __shared__ float tile[64][65];
    const int slot = blockIdx.z;
    const int k0 = blockIdx.x * 64;
    const int n0 = blockIdx.y * 64;
    const float* src = (slot < 4) ? (Wsh + (size_t)slot * kD * kDE)
                                  : (Wsp + (size_t)(slot - 4) * kD * kDE);
    const int tid = threadIdx.x;
    const int lr = tid >> 4, lc = (tid & 15) * 4;
#pragma unroll
    for (int i = 0; i < 4; i++) {
        const float4 v = *(const float4*)&src[(size_t)(k0 + lr + i * 16) * kDE + n0 + lc];
        tile[lr + i * 16][lc + 0] = v.x;
        tile[lr + i * 16][lc + 1] = v.y;
        tile[lr + i * 16][lc + 2] = v.z;
        tile[lr + i * 16][lc + 3] = v.w;
    }
    __syncthreads();
    const int wn = tid >> 2, wk = (tid & 3) * 16;
    unsigned short* dst = Wt + (size_t)slot * kDE * kD + (size_t)(n0 + wn) * kD + k0 + wk;
#pragma unroll
    for (int j = 0; j < 4; j++) {
        ushort4 h;
        h.x = f2bf(tile[wk + j * 4 + 0][wn]);
        h.y = f2bf(tile[wk + j * 4 + 1][wn]);
        h.z = f2bf(tile[wk + j * 4 + 2][wn]);
        h.w = f2bf(tile[wk + j * 4 + 3][wn]);
        *(ushort4*)(dst + j * 4) = h;
    }
}

// ------------- fused x fp32->bf16 conversion + gate softmax ---------------
__global__ __launch_bounds__(256) void conv_gate(
    const float* __restrict__ x0, const float* __restrict__ x1,
    const float* __restrict__ Wg, const float* __restrict__ bg,
    unsigned short* __restrict__ xb, float* __restrict__ g) {
    const int wid = threadIdx.x >> 6, lane = threadIdx.x & 63;
    const int r = blockIdx.x * 4 + wid;
    const int t = r >> 14, b = r & 16383;
    const float* xrow = (t ? x1 : x0) + (size_t)b * kD;
    unsigned short* xbrow = xb + (size_t)(t * kB + b) * kD;
    const float* Wgt = Wg + t * kD * 8;
    float p[8] = {0.f,0.f,0.f,0.f,0.f,0.f,0.f,0.f};
#pragma unroll
    for (int it = 0; it < 4; it++) {
        const int d0 = it * 256 + lane * 4;
        const float4 v = *(const float4*)(xrow + d0);
        ushort4 h;
        h.x = f2bf(v.x); h.y = f2bf(v.y); h.z = f2bf(v.z); h.w = f2bf(v.w);
        *(ushort4*)(xbrow + d0) = h;
        const float xv[4] = {v.x, v.y, v.z, v.w};
#pragma unroll
        for (int j = 0; j < 4; j++) {
            const float* wrow = Wgt + (size_t)(d0 + j) * 8;
            const float4 wa = *(const float4*)wrow;
            const float4 wb = *(const float4*)(wrow + 4);
            p[0] += xv[j] * wa.x; p[1] += xv[j] * wa.y;
            p[2] += xv[j] * wa.z; p[3] += xv[j] * wa.w;
            p[4] += xv[j] * wb.x; p[5] += xv[j] * wb.y;
            p[6] += xv[j] * wb.z; p[7] += xv[j] * wb.w;
        }
    }
#pragma unroll
    for (int e = 0; e < 8; e++) {
        float v = p[e];
#pragma unroll
        for (int s = 1; s < 64; s <<= 1) v += __shfl_xor(v, s, 64);
        p[e] = v;
    }
    float lg[8];
#pragma unroll
    for (int e = 0; e < 8; e++) lg[e] = p[e] + bg[t * 8 + e];
    float mx = lg[0];
#pragma unroll
    for (int e = 1; e < 8; e++) mx = fmaxf(mx, lg[e]);
    float s = 0.f;
#pragma unroll
    for (int e = 0; e < 8; e++) { lg[e] = __expf(lg[e] - mx); s += lg[e]; }
    const float inv = 1.f / s;
    if (lane == 0) {
        float* gp = g + (size_t)(t * kB + b) * 8;
        float4 g0 = {lg[0]*inv, lg[1]*inv, lg[2]*inv, lg[3]*inv};
        float4 g1 = {lg[4]*inv, lg[5]*inv, lg[6]*inv, lg[7]*inv};
        *(float4*)gp = g0;
        *(float4*)(gp + 4) = g1;
    }
}

// ------------------- fused MoE GEMM (R6 + L2-pinned B) ---------------------
// Identical compute/schedule to the proven 305us kernel. ONLY the block->work
// mapping changed: ct = bid & 7. Consecutive bids round-robin XCDs, so each
// XCD owns ONE 64-col slice (ct = its index) for the whole dispatch: its B
// working set = 12 slots x 128 KB = 1.5 MB, L2-resident permanently.
// B L3 traffic drops 2 GB -> 12 MB; A streams with unit reuse per pass.
__global__ __launch_bounds__(512, 2) void moe_gemm(
    const unsigned short* __restrict__ xb, const unsigned short* __restrict__ Wt,
    const float* __restrict__ g, const float* __restrict__ bsh,
    const float* __restrict__ bsp, float* __restrict__ out) {
    __shared__ __align__(16) unsigned short As[2][128 * 64];      // 32 KB
    __shared__ __align__(16) unsigned short Bs[2][8 * 64 * 64];   // 128 KB

    // L2-locality mapping: XCD (= bid&7, round-robin dispatch) keeps ct fixed;
    // rt varies fastest within an XCD; t slowest. Bijective over 2048 blocks.
    const int bid = blockIdx.x;
    const int ct = bid & 7;
    const int rt = (bid >> 3) & 127;
    const int t  = bid >> 10;
    const int n0 = ct * 64;

    const int tid = threadIdx.x, wid = tid >> 6, lane = tid & 63;
    const int wr = wid >> 2, wc = wid & 3;

    // staging (pre-swizzled global source, linear LDS dest — rule #21)
    const int swzChunk = ((lane & 7) ^ ((lane >> 3) & 7)) * 8;
    const unsigned short* aSrc = xb + (size_t)t * kB * kD +
        (size_t)(rt * 128 + wid * 16 + (lane >> 3)) * kD + swzChunk;
    const int slot = (wid < 4) ? wid : (4 + t * 4 + (wid - 4));
    const unsigned short* bSrc = Wt + (size_t)slot * kDE * kD +
        (size_t)(n0 + (lane >> 3)) * kD + swzChunk;

    // fragment read offsets
    const int rAbase = (wr * 64 + (lane & 15)) * 64;
    const int bOff   = (wc * 16 + (lane & 15)) * 64;
    const int lx     = lane & 7;
    const int kg     = lane >> 4;

    f32x4 acc[8][4];
#pragma unroll
    for (int e = 0; e < 8; e++)
#pragma unroll
        for (int m = 0; m < 4; m++) acc[e][m] = (f32x4){0.f, 0.f, 0.f, 0.f};

#define STAGE(buf, kt)                                                        \
    {                                                                         \
        const int k0_ = (kt) * 64;                                            \
        _Pragma("unroll")                                                     \
        for (int i = 0; i < 2; i++)                                           \
            async16(&As[buf][wid * 1024 + i * 512], aSrc + k0_ + i * 8 * kD); \
        _Pragma("unroll")                                                     \
        for (int j = 0; j < 8; j++)                                           \
            async16(&Bs[buf][wid * 4096 + j * 512], bSrc + k0_ + j * 8 * kD); \
    }

#define COMPUTE(buf)                                                          \
    {                                                                         \
        _Pragma("unroll")                                                     \
        for (int ks = 0; ks < 2; ks++) {                                      \
            const int p8 = ((ks * 4 + kg) ^ lx) * 8;                          \
            bf16x8 af[4];                                                     \
            _Pragma("unroll")                                                 \
            for (int m = 0; m < 4; m++)                                       \
                af[m] = *(const bf16x8*)&As[buf][rAbase + m * 1024 + p8];     \
            _Pragma("unroll")                                                 \
            for (int e = 0; e < 8; e++) {                                     \
                bf16x8 bf = *(const bf16x8*)&Bs[buf][e * 4096 + bOff + p8];   \
                _Pragma("unroll")                                             \
                for (int m = 0; m < 4; m++)                                   \
                    acc[e][m] = __builtin_amdgcn_mfma_f32_16x16x32_bf16(      \
                        af[m], bf, acc[e][m], 0, 0, 0);                       \
            }                                                                 \
        }                                                                     \
    }

    STAGE(0, 0);                                   // 10 loads in flight
    for (int kt2 = 0; kt2 < 8; ++kt2) {
        STAGE(1, kt2 * 2 + 1);
        asm volatile("s_waitcnt vmcnt(10)" ::: "memory");
        __builtin_amdgcn_s_barrier();
        COMPUTE(0);
        __builtin_amdgcn_s_barrier();
        STAGE(0, (kt2 * 2 + 2) & 15);              // last iter restages t0 (benign)
        asm volatile("s_waitcnt vmcnt(10)" ::: "memory");
        __builtin_amdgcn_s_barrier();
        COMPUTE(1);
        __builtin_amdgcn_s_barrier();
    }
    asm volatile("s_waitcnt vmcnt(0)" ::: "memory");

#undef STAGE
#undef COMPUTE

    // ---- epilogue: out = sum_e g_e * relu(acc[e] + bias_e), bias direct ----
    const int col = n0 + wc * 16 + (lane & 15);
    float bv[8];
#pragma unroll
    for (int e = 0; e < 8; e++)
        bv[e] = (e < 4) ? bsh[e * kDE + col] : bsp[(t * 4 + (e - 4)) * kDE + col];

#pragma unroll
    for (int m = 0; m < 4; m++) {
        const int r0 = rt * 128 + wr * 64 + m * 16 + kg * 4;
#pragma unroll
        for (int q = 0; q < 4; q++) {
            const float* gp = g + ((size_t)t * kB + r0 + q) * 8;
            const float4 ga = *(const float4*)gp;
            const float4 gb = *(const float4*)(gp + 4);
            float s = ga.x * fmaxf(acc[0][m][q] + bv[0], 0.f)
                    + ga.y * fmaxf(acc[1][m][q] + bv[1], 0.f)
                    + ga.z * fmaxf(acc[2][m][q] + bv[2], 0.f)
                    + ga.w * fmaxf(acc[3][m][q] + bv[3], 0.f)
                    + gb.x * fmaxf(acc[4][m][q] + bv[4], 0.f)
                    + gb.y * fmaxf(acc[5][m][q] + bv[5], 0.f)
                    + gb.z * fmaxf(acc[6][m][q] + bv[6], 0.f)
                    + gb.w * fmaxf(acc[7][m][q] + bv[7], 0.f);
            out[((size_t)(r0 + q) * 2 + t) * kDE + col] = s;
        }
    }
}

extern "C" void kernel_launch(void* const* d_in, const int* in_sizes, int n_in,
                              void* d_out, int out_size, void* d_ws, size_t ws_size,
                              hipStream_t stream) {
    const float* x0  = (const float*)d_in[0];
    const float* x1  = (const float*)d_in[1];
    const float* Wsh = (const float*)d_in[2];
    const float* bsh = (const float*)d_in[3];
    const float* Wsp = (const float*)d_in[4];
    const float* bsp = (const float*)d_in[5];
    const float* Wg  = (const float*)d_in[6];
    const float* bg  = (const float*)d_in[7];
    float* out = (float*)d_out;

    // ws layout (bytes): xb 67108864 | Wt 12582912 | g 1048576
    char* ws = (char*)d_ws;
    unsigned short* xb = (unsigned short*)ws;
    unsigned short* Wt = (unsigned short*)(ws + 67108864);
    float* g  = (float*)(ws + 67108864 + 12582912);

    prep_w<<<dim3(16, 8, 12), dim3(256), 0, stream>>>(Wsh, Wsp, Wt);
    conv_gate<<<dim3(8192), dim3(256), 0, stream>>>(x0, x1, Wg, bg, xb, g);
    moe_gemm<<<dim3(2048), dim3(512), 0, stream>>>(xb, Wt, g, bsh, bsp, out);
}